// Round 8
// baseline (228.237 us; speedup 1.0000x reference)
//
#include <hip/hip_runtime.h>

// FindInstancePeaks: fused conv backbone + global peak finding.
// crops (128,192,192,1) f32 -> conv1 3x3 s2 SAME (1->32) + relu
//                          -> conv2 3x3 s1 SAME (32->17) = cms (128,96,96,17)
// -> per (b,n): argmax over 96x96, quarter-pixel sign refine, *2, NaN<0.2.
//
// R16: R10-R15 invariant: busy ~120us (1.4x counted), idle ~30% independent
// of occupancy (54% / 58% / 29.5% all give ~170-200us wall). The one
// constant across all variants: per-(cl,k) weight loads from a computed
// "uniform" address, 288x per thread. If divergence analysis fails ->
// per-lane loads + v_movs (= the busy gap) + vmcnt stalls at identical
// code positions in every wave (= occupancy-independent idle). Even if
// scalar: SMEM shares lgkmcnt with DS, completes out-of-order -> per-tap
// lgkmcnt(0) drain with zero prefetch distance.
// Fix, holding R15's structure fixed (single-theory test):
//  (1) readfirstlane on ALL weight/bias offsets -> offsets provably SGPR.
//  (2) conv2 weight double-buffer w[2][17]: tap k+1 issues before tap k's
//      51 FMAs -> >=102cy prefetch distance. Statically indexed.
//  (3) conv1 per-pixel state (in_off/out_off/vf) hoisted out of g-loop.
// Live ~127 <= 170 cap @ (256,3): no spill risk. Accumulation order
// unchanged (c asc, k asc, q asc) -> bit-exact (absmax 0.0).

#define NCH 17
#define C1 32
#define TW 24           // tile width
#define TH 32           // tile height
#define HT_W 26         // h cols needed (TW+2)
#define HT_H 34         // h rows needed (TH+2)
#define HSTR 28         // s_h col stride
#define IN_W 53         // input patch cols: 2*HT_W+1
#define IN_H 69         // input patch rows: 2*HT_H+1
#define CG 8            // conv1 channels per group
#define NG 4            // groups
#define NHPX (HT_H * HT_W)   // 884 h-pixels per block
#define SH_PLANE (HT_H * HSTR)

__device__ __forceinline__ unsigned long long pack_key(float v, unsigned flat) {
    unsigned ub = __float_as_uint(v);
    ub = (ub & 0x80000000u) ? ~ub : (ub | 0x80000000u);   // monotone float->uint
    return ((unsigned long long)ub << 32) | (unsigned)(~flat); // ~flat: ties -> lowest idx
}

__global__ __launch_bounds__(256, 3) void conv_peaks_kernel(
    const float* __restrict__ crops, const float* __restrict__ W1g,
    const float* __restrict__ b1g, const float* __restrict__ W2g,
    const float* __restrict__ b2g, unsigned long long* __restrict__ peaks) {
    __shared__ __align__(16) float s_in[IN_H * IN_W];        // 14628 B
    __shared__ __align__(16) float s_h[CG * SH_PLANE];       // 30464 B

    const int t = threadIdx.x;
    const int b = blockIdx.y;
    const int ty0 = (blockIdx.x >> 2) * TH;   // 0,32,64
    const int tx0 = (blockIdx.x & 3) * TW;    // 0,24,48,72
    const int iy0 = 2 * ty0 - 2;
    const int ix0 = 2 * tx0 - 2;
    const float* cb = crops + b * 192 * 192;

    // --- stage input patch (zero-padded at image borders) ---
    for (int p = t; p < IN_H * IN_W; p += 256) {
        int r = p / IN_W, cc = p - r * IN_W;
        int iy = iy0 + r, ix = ix0 + cc;
        float v = 0.f;
        if (iy >= 0 && ix >= 0 && iy < 192 && ix < 192) v = cb[iy * 192 + ix];
        s_in[p] = v;
    }

    // --- conv1 per-pixel state, group-invariant: hoisted out of g-loop ---
    int in_off[4], out_off[4];
    float vf[4];
#pragma unroll
    for (int i = 0; i < 4; ++i) {
        int p = t + i * 256;
        int r = p / HT_W, cc = p - r * HT_W;
        int hy = ty0 - 1 + r, hx = tx0 - 1 + cc;
        vf[i] = (hy >= 0 && hy < 96 && hx >= 0 && hx < 96) ? 1.f : 0.f;
        in_off[i] = 2 * r * IN_W + 2 * cc;
        out_off[i] = r * HSTR + cc;
    }

    // thread -> 3 contiguous pixels: row ly, cols lx0..lx0+2
    const int ly = t >> 3;            // 0..31
    const int lx0 = (t & 7) * 3;      // 0,3,...,21
    float acc[NCH][3];
#pragma unroll
    for (int n = 0; n < NCH; ++n)
#pragma unroll
        for (int p = 0; p < 3; ++p) acc[n][p] = 0.f;

#pragma unroll 1
    for (int g = 0; g < NG; ++g) {
        __syncthreads();   // staging done / prev conv2 reads done

        // conv1 + relu for this group's 8 channels: in9 loaded ONCE per
        // pixel, reused across 8 channels. Weight base forced uniform.
#pragma unroll
        for (int i = 0; i < 4; ++i) {
            if (i < 3 || t < NHPX - 768) {
                const float* ip = s_in + in_off[i];
                float in9[9];
#pragma unroll
                for (int qy = 0; qy < 3; ++qy)
#pragma unroll
                    for (int qx = 0; qx < 3; ++qx)
                        in9[qy * 3 + qx] = ip[qy * IN_W + qx];
#pragma unroll
                for (int cl = 0; cl < CG; ++cl) {
                    const int c = __builtin_amdgcn_readfirstlane(g * CG + cl);
                    const float* w1p = W1g + c;       // + q*C1 imm offsets
                    float a = b1g[c];
#pragma unroll
                    for (int q = 0; q < 9; ++q)
                        a = fmaf(in9[q], w1p[q * C1], a);
                    s_h[cl * SH_PLANE + out_off[i]] = fmaxf(a, 0.f) * vf[i];
                }
            }
        }
        __syncthreads();   // conv1(g) visible

        // conv2 partial: per cl: 15 ds_read_b32, then 9 taps x 3 px x 17 ch
        // register FMAs. Weights: double-buffered w[2][17], offset forced
        // SGPR via readfirstlane; tap k+1 issues before tap k's FMAs.
#pragma unroll 1
        for (int cl = 0; cl < CG; ++cl) {
            const float* hp = s_h + cl * SH_PLANE + ly * HSTR + lx0;
            float hr[3][5];
#pragma unroll
            for (int ky = 0; ky < 3; ++ky)
#pragma unroll
                for (int j = 0; j < 5; ++j) hr[ky][j] = hp[ky * HSTR + j];
            const int c = g * CG + cl;

            float w[2][NCH];
            {
                const float* wb =
                    W2g + __builtin_amdgcn_readfirstlane((0 * C1 + c) * NCH);
#pragma unroll
                for (int n = 0; n < NCH; ++n) w[0][n] = wb[n];
            }
#pragma unroll
            for (int k = 0; k < 9; ++k) {
                if (k < 8) {
                    const float* wb = W2g + __builtin_amdgcn_readfirstlane(
                                                ((k + 1) * C1 + c) * NCH);
#pragma unroll
                    for (int n = 0; n < NCH; ++n) w[(k + 1) & 1][n] = wb[n];
                }
                const int ky = k / 3, kx = k - ky * 3;
#pragma unroll
                for (int p = 0; p < 3; ++p) {
                    const float h = hr[ky][kx + p];
#pragma unroll
                    for (int n = 0; n < NCH; ++n)
                        acc[n][p] = fmaf(h, w[k & 1][n], acc[n][p]);
                }
            }
        }
    }

    // --- per-channel argmax: in-thread max over 3 px, then wave reduce ---
    const int yg = ty0 + ly, xg = tx0 + lx0;
    const int lane = t & 63;
#pragma unroll
    for (int n = 0; n < NCH; ++n) {
        const float bb = b2g[n];
        unsigned long long pk = pack_key(acc[n][0] + bb, (unsigned)(yg * 96 + xg));
#pragma unroll
        for (int p = 1; p < 3; ++p) {
            unsigned long long o = pack_key(acc[n][p] + bb, (unsigned)(yg * 96 + xg + p));
            if (o > pk) pk = o;
        }
#pragma unroll
        for (int off = 32; off; off >>= 1) {
            unsigned long long o = __shfl_down(pk, off, 64);
            if (o > pk) pk = o;
        }
        if (lane == 0) atomicMax(&peaks[b * NCH + n], pk);
    }
}

// One 64-lane wave per (b,n): decode peak, recompute 4 clipped neighbor cms
// values (b2 cancels in the sign differences), emit (x,y,val).
__global__ __launch_bounds__(64) void refine_kernel(
    const float* __restrict__ crops, const float* __restrict__ W1g,
    const float* __restrict__ b1g, const float* __restrict__ W2g,
    const unsigned long long* __restrict__ peaks, float* __restrict__ out) {
    const int bn = blockIdx.x;          // 0..128*17-1
    const int b = bn / NCH, n = bn % NCH;
    const int lane = threadIdx.x;

    unsigned long long pk = peaks[bn];
    unsigned key = (unsigned)(pk >> 32);
    unsigned fbits = (key & 0x80000000u) ? (key ^ 0x80000000u) : ~key;
    float val = __uint_as_float(fbits);
    int flat = (int)(~(unsigned)(pk & 0xffffffffu));
    int yi = flat / 96, xi = flat - yi * 96;

    // neighbor j: 0:(yi,xi+1) 1:(yi,xi-1) 2:(yi+1,xi) 3:(yi-1,xi), clipped
    const int j = lane >> 4;
    int yy = yi + ((j == 2) ? 1 : 0) - ((j == 3) ? 1 : 0);
    int xx = xi + ((j == 0) ? 1 : 0) - ((j == 1) ? 1 : 0);
    yy = min(max(yy, 0), 95);
    xx = min(max(xx, 0), 95);

    // hoist 7x7 crops patch: rows 2yy-2..2yy+4, cols 2xx-2..2xx+4
    const float* cb = crops + b * 192 * 192;
    float pat[7][7];
#pragma unroll
    for (int r = 0; r < 7; ++r) {
        int iy = 2 * yy - 2 + r;
#pragma unroll
        for (int s = 0; s < 7; ++s) {
            int ix = 2 * xx - 2 + s;
            pat[r][s] = (iy >= 0 && iy < 192 && ix >= 0 && ix < 192)
                            ? cb[iy * 192 + ix] : 0.f;
        }
    }

    float part = 0.f;
#pragma unroll
    for (int ci = 0; ci < 2; ++ci) {
        const int c = (lane & 15) + ci * 16;
        const float bias = b1g[c];
        float w1[9];
#pragma unroll
        for (int q = 0; q < 9; ++q) w1[q] = W1g[q * C1 + c];
#pragma unroll
        for (int dy = 0; dy < 3; ++dy) {
#pragma unroll
            for (int dx = 0; dx < 3; ++dx) {
                int hy = yy - 1 + dy, hx = xx - 1 + dx;
                if (hy >= 0 && hy < 96 && hx >= 0 && hx < 96) {
                    float a = bias;
#pragma unroll
                    for (int qy = 0; qy < 3; ++qy)
#pragma unroll
                        for (int qx = 0; qx < 3; ++qx)
                            a = fmaf(pat[2 * dy + qy][2 * dx + qx],
                                     w1[qy * 3 + qx], a);
                    float hval = fmaxf(a, 0.f);
                    part = fmaf(hval, W2g[((dy * 3 + dx) * C1 + c) * NCH + n], part);
                }
            }
        }
    }
    // sum the 16 lanes of each neighbor group
    for (int off = 8; off; off >>= 1) part += __shfl_down(part, off, 16);
    float g0 = __shfl(part, 0, 64);
    float g1 = __shfl(part, 16, 64);
    float g2 = __shfl(part, 32, 64);
    float g3 = __shfl(part, 48, 64);

    if (lane == 0) {
        float d0 = g0 - g1, d1 = g2 - g3;
        float sx = (d0 > 0.f) ? 1.f : ((d0 < 0.f) ? -1.f : 0.f);
        float sy = (d1 > 0.f) ? 1.f : ((d1 < 0.f) ? -1.f : 0.f);
        float px = ((float)xi + 0.25f * sx) * 2.f;
        float py = ((float)yi + 0.25f * sy) * 2.f;
        if (!(val >= 0.2f)) {
            px = __int_as_float(0x7fc00000);
            py = __int_as_float(0x7fc00000);
        }
        out[bn * 3 + 0] = px;
        out[bn * 3 + 1] = py;
        out[bn * 3 + 2] = val;
    }
}

extern "C" void kernel_launch(void* const* d_in, const int* in_sizes, int n_in,
                              void* d_out, int out_size, void* d_ws, size_t ws_size,
                              hipStream_t stream) {
    const float* crops = (const float*)d_in[0];
    const float* W1 = (const float*)d_in[1];
    const float* b1 = (const float*)d_in[2];
    const float* W2 = (const float*)d_in[3];
    const float* b2 = (const float*)d_in[4];
    float* out = (float*)d_out;
    unsigned long long* peaks = (unsigned long long*)d_ws;

    hipMemsetAsync(d_ws, 0, 128 * NCH * sizeof(unsigned long long), stream);

    dim3 gridB(12, 128);  // 4x3 tiles of 24x32 over 96x96, per image
    conv_peaks_kernel<<<gridB, 256, 0, stream>>>(crops, W1, b1, W2, b2, peaks);
    refine_kernel<<<128 * NCH, 64, 0, stream>>>(crops, W1, b1, W2, peaks, out);
}